// Round 2
// baseline (343.843 us; speedup 1.0000x reference)
//
#include <hip/hip_runtime.h>

#define NSEQ 4096
#define BATCH 2
#define ROWS (BATCH * NSEQ)   // 8192
#define NH 8
#define DHD 32
#define VROWS 48              // 32 V rows + ones row + 15 zero rows (MFMA ones-trick)

typedef __attribute__((ext_vector_type(8))) short bf16x8;
typedef __attribute__((ext_vector_type(4))) float f32x4;

static __device__ __forceinline__ ushort f2bf(float f) {
    union { float f; uint u; } v; v.f = f;
    uint u = v.u;
    uint r = (u + 0x7fffu + ((u >> 16) & 1u)) >> 16;   // RTNE
    return (ushort)r;
}

// ---------------- prep: x fp32 -> bf16 ----------------
__global__ __launch_bounds__(256) void k_convert_x(const float* __restrict__ x,
                                                   ushort* __restrict__ xb) {
    int i = (blockIdx.x * 256 + threadIdx.x) * 4;   // total 2097152 elems
    float4 v = *(const float4*)(x + i);
    ushort4 o;
    o.x = f2bf(v.x); o.y = f2bf(v.y); o.z = f2bf(v.z); o.w = f2bf(v.w);
    *(ushort4*)(xb + i) = o;
}

// ---------------- prep: W [K=256][ncols] fp32 -> Wt [ncols][256] bf16 ----------------
__global__ __launch_bounds__(256) void k_transpose_w(const float* __restrict__ w,
                                                     ushort* __restrict__ wt, int ncols) {
    int n = blockIdx.x * 256 + threadIdx.x;
    int k = blockIdx.y;   // 0..255
    wt[n * 256 + k] = f2bf(w[k * ncols + n]);
}

// ---------------- init: vT pad rows 32..47 (row 32 = 1.0, rest = 0) ----------------
__global__ __launch_bounds__(256) void k_init_vpad(ushort* __restrict__ vT) {
    int i = blockIdx.x * 256 + threadIdx.x;   // 262144 threads, 4 elems each
    int e = i * 4;                            // over 16 bh * 16 rows * 4096
    int bh = e >> 16;
    int rem = e & 65535;
    int rr = rem >> 12;
    int n = rem & 4095;
    ushort val = (rr == 0) ? (ushort)0x3F80 : (ushort)0;
    ushort4 o = {val, val, val, val};
    *(ushort4*)(vT + ((size_t)bh * VROWS + 32 + rr) * NSEQ + n) = o;
}

// ---------------- QKV GEMM: [8192x256]bf16 @ Wt[768][256] + bias ----------------
// writes: qk [8192][512] (cols 0..255 = Q*(1/16), 256..511 = K), vT [16][48][4096]
__global__ __launch_bounds__(256) void k_qkv(const ushort* __restrict__ xb,
                                             const ushort* __restrict__ wt,
                                             const float* __restrict__ bias,
                                             ushort* __restrict__ qk,
                                             ushort* __restrict__ vT) {
    int w = threadIdx.x >> 6, lane = threadIdx.x & 63;
    int lhi = lane >> 4, llo = lane & 15;
    int row0 = blockIdx.x * 64 + w * 16;
    int n0 = blockIdx.y * 64;

    f32x4 acc[4] = {};
#pragma unroll
    for (int ks = 0; ks < 8; ++ks) {
        int k0 = ks * 32 + lhi * 8;
        bf16x8 a = *(const bf16x8*)(xb + (row0 + llo) * 256 + k0);
#pragma unroll
        for (int fn = 0; fn < 4; ++fn) {
            bf16x8 b = *(const bf16x8*)(wt + (n0 + fn * 16 + llo) * 256 + k0);
            acc[fn] = __builtin_amdgcn_mfma_f32_16x16x32_bf16(a, b, acc[fn], 0, 0, 0);
        }
    }
#pragma unroll
    for (int fn = 0; fn < 4; ++fn) {
        int cg = n0 + fn * 16 + llo;
        int three = cg >> 8, rem = cg & 255;
        float bv = bias[cg];
#pragma unroll
        for (int r = 0; r < 4; ++r) {
            int row = row0 + lhi * 4 + r;
            float v = acc[fn][r] + bv;
            if (three == 0) {
                qk[row * 512 + rem] = f2bf(v * 0.0625f);   // pre-scale Q by C^-0.5 = 1/16
            } else if (three == 1) {
                qk[row * 512 + 256 + rem] = f2bf(v);
            } else {
                int b = row >> 12, n = row & 4095;
                int h = rem >> 5, dh = rem & 31;
                vT[((size_t)(b * NH + h) * VROWS + dh) * NSEQ + n] = f2bf(v);
            }
        }
    }
}

// ---------------- flash attention: 1 wave = 16 q-rows, KV tiles of 64 ----------------
// deferred-max (THR=8), l via ones-row MFMA, cvt_pk bf16 packing. Fast path: 0 shuffles.
__global__ __launch_bounds__(256) void k_attn(const ushort* __restrict__ qk,
                                              const ushort* __restrict__ vT,
                                              ushort* __restrict__ attn_out) {
    __shared__ __align__(16) ushort p_lds[4][1024];   // per-wave 16x64 bf16 P tile (swizzled)
    int w = threadIdx.x >> 6, lane = threadIdx.x & 63;
    int lhi = lane >> 4, llo = lane & 15;
    int wid = blockIdx.x * 4 + w;          // 0..4095
    int bh = wid >> 8;                     // 0..15 (b*8+h)
    int qt = wid & 255;
    int b = bh >> 3, h = bh & 7;
    int q0 = qt * 16;

    const ushort* qbase = qk + (size_t)(b * NSEQ) * 512 + h * DHD;
    const ushort* kbase = qbase + 256;
    const ushort* vbase = vT + (size_t)bh * VROWS * NSEQ;
    const ushort* pv0 = vbase + llo * NSEQ;
    const ushort* pv1 = vbase + (llo + 16) * NSEQ;
    const ushort* pv2 = vbase + (llo + 32) * NSEQ;   // ones/zero rows
    const ushort* pk0 = kbase + llo * 512 + lhi * 8;

    bf16x8 qf = *(const bf16x8*)(qbase + (q0 + llo) * 512 + lhi * 8);
    f32x4 acc0 = {}, acc1 = {}, acc2 = {};
    const float L2E = 1.4426950408889634f;
    float mrun = 0.f;      // deferred running max for q-row llo
    float nmL2E = 0.f;     // -mrun * L2E
    float mthr = 8.f;      // mrun + THR
    char* pl = (char*)&p_lds[w][0];
    int swz = (llo & 7) << 4;
    const f32x4 zf = {0.f, 0.f, 0.f, 0.f};

    for (int kv = 0; kv < NSEQ; kv += 64) {
        // ---- S^T tile: mfma(K, Q) -> lane holds S[qrow=llo][key = kv + st*16 + lhi*4 + r]
        f32x4 sf[4];
#pragma unroll
        for (int st = 0; st < 4; ++st) {
            bf16x8 kf = *(const bf16x8*)(pk0 + (kv + st * 16) * 512);
            sf[st] = __builtin_amdgcn_mfma_f32_16x16x32_bf16(kf, qf, zf, 0, 0, 0);
        }
        // ---- V loads (independent of softmax -> issue early)
        bf16x8 va[2][3];
#pragma unroll
        for (int kt = 0; kt < 2; ++kt) {
            int o = kv + kt * 32 + lhi * 8;
            va[kt][0] = *(const bf16x8*)(pv0 + o);
            va[kt][1] = *(const bf16x8*)(pv1 + o);
            va[kt][2] = *(const bf16x8*)(pv2 + o);
        }
        // ---- per-lane partial max (tree), deferred-max check (no shuffles in fast path)
        float t0 = fmaxf(fmaxf(sf[0][0], sf[0][1]), fmaxf(sf[0][2], sf[0][3]));
        float t1 = fmaxf(fmaxf(sf[1][0], sf[1][1]), fmaxf(sf[1][2], sf[1][3]));
        float t2 = fmaxf(fmaxf(sf[2][0], sf[2][1]), fmaxf(sf[2][2], sf[2][3]));
        float t3 = fmaxf(fmaxf(sf[3][0], sf[3][1]), fmaxf(sf[3][2], sf[3][3]));
        float tm = fmaxf(fmaxf(t0, t1), fmaxf(t2, t3));
        if (!__all(tm <= mthr)) {
            // slow path (rare): true row max, rescale accumulators
            float rmax = fmaxf(tm, __shfl_xor(tm, 16));
            rmax = fmaxf(rmax, __shfl_xor(rmax, 32));        // row llo tile-max
            float mnew = fmaxf(mrun, rmax);
            float corr = __builtin_amdgcn_exp2f((mrun - mnew) * L2E);
            mrun = mnew; nmL2E = -mrun * L2E; mthr = mrun + 8.f;
#pragma unroll
            for (int r = 0; r < 4; ++r) {
                float fc = __shfl(corr, lhi * 4 + r);
                acc0[r] *= fc; acc1[r] *= fc; acc2[r] *= fc;
            }
        }
        // ---- P = exp2(S*L2E - m*L2E), pack via v_cvt_pk_bf16_f32, store to LDS
#pragma unroll
        for (int st = 0; st < 4; ++st) {
            float p0 = __builtin_amdgcn_exp2f(__builtin_fmaf(sf[st][0], L2E, nmL2E));
            float p1 = __builtin_amdgcn_exp2f(__builtin_fmaf(sf[st][1], L2E, nmL2E));
            float p2 = __builtin_amdgcn_exp2f(__builtin_fmaf(sf[st][2], L2E, nmL2E));
            float p3 = __builtin_amdgcn_exp2f(__builtin_fmaf(sf[st][3], L2E, nmL2E));
            uint2 pkv;
            asm("v_cvt_pk_bf16_f32 %0, %1, %2" : "=v"(pkv.x) : "v"(p0), "v"(p1));
            asm("v_cvt_pk_bf16_f32 %0, %1, %2" : "=v"(pkv.y) : "v"(p2), "v"(p3));
            int ub = st * 32 + lhi * 8;
            *(uint2*)(pl + llo * 128 + (ub ^ swz)) = pkv;
        }
        // ---- PV: A = P[16q x 64k] from LDS, B = V^T rows; acc2 accumulates row-sums (l)
#pragma unroll
        for (int kt = 0; kt < 2; ++kt) {
            int ub = kt * 64 + lhi * 16;
            bf16x8 pf = *(const bf16x8*)(pl + llo * 128 + (ub ^ swz));
            acc0 = __builtin_amdgcn_mfma_f32_16x16x32_bf16(pf, va[kt][0], acc0, 0, 0, 0);
            acc1 = __builtin_amdgcn_mfma_f32_16x16x32_bf16(pf, va[kt][1], acc1, 0, 0, 0);
            acc2 = __builtin_amdgcn_mfma_f32_16x16x32_bf16(pf, va[kt][2], acc2, 0, 0, 0);
        }
    }
    // epilogue: l[q] = acc2 col 0 = lane (llo=0, same lhi)
#pragma unroll
    for (int r = 0; r < 4; ++r) {
        float ls = __shfl(acc2[r], lhi * 16);
        float li = 1.f / ls;
        int row = q0 + lhi * 4 + r;
        size_t orow = ((size_t)(b * NSEQ) + row) * 256 + h * DHD;
        attn_out[orow + llo] = f2bf(acc0[r] * li);
        attn_out[orow + 16 + llo] = f2bf(acc1[r] * li);
    }
}

// ---------------- proj GEMM: [8192x256]bf16 @ Wt[256][256] + bias -> fp32 ----------------
__global__ __launch_bounds__(256) void k_proj(const ushort* __restrict__ aout,
                                              const ushort* __restrict__ wt,
                                              const float* __restrict__ bias,
                                              float* __restrict__ out) {
    int w = threadIdx.x >> 6, lane = threadIdx.x & 63;
    int lhi = lane >> 4, llo = lane & 15;
    int row0 = blockIdx.x * 64 + w * 16;
    int n0 = blockIdx.y * 64;

    f32x4 acc[4] = {};
#pragma unroll
    for (int ks = 0; ks < 8; ++ks) {
        int k0 = ks * 32 + lhi * 8;
        bf16x8 a = *(const bf16x8*)(aout + (row0 + llo) * 256 + k0);
#pragma unroll
        for (int fn = 0; fn < 4; ++fn) {
            bf16x8 b = *(const bf16x8*)(wt + (n0 + fn * 16 + llo) * 256 + k0);
            acc[fn] = __builtin_amdgcn_mfma_f32_16x16x32_bf16(a, b, acc[fn], 0, 0, 0);
        }
    }
#pragma unroll
    for (int fn = 0; fn < 4; ++fn) {
        int cg = n0 + fn * 16 + llo;
        float bv = bias[cg];
#pragma unroll
        for (int r = 0; r < 4; ++r) {
            int row = row0 + lhi * 4 + r;
            out[(size_t)row * 256 + cg] = acc[fn][r] + bv;
        }
    }
}

extern "C" void kernel_launch(void* const* d_in, const int* in_sizes, int n_in,
                              void* d_out, int out_size, void* d_ws, size_t ws_size,
                              hipStream_t stream) {
    const float* x     = (const float*)d_in[0];
    const float* Wqkv  = (const float*)d_in[1];
    const float* bqkv  = (const float*)d_in[2];
    const float* Wproj = (const float*)d_in[3];
    const float* bproj = (const float*)d_in[4];
    float* out = (float*)d_out;

    char* ws = (char*)d_ws;
    ushort* xb     = (ushort*)(ws);                 // 8192*256*2   = 4,194,304
    ushort* wqkvT  = (ushort*)(ws + 4194304);       // 768*256*2    =   393,216
    ushort* wprojT = (ushort*)(ws + 4587520);       // 256*256*2    =   131,072
    ushort* qkbuf  = (ushort*)(ws + 4718592);       // 8192*512*2   = 8,388,608
    ushort* vT     = (ushort*)(ws + 13107200);      // 16*48*4096*2 = 6,291,456
    ushort* aoutb  = (ushort*)(ws + 19398656);      // 8192*256*2   = 4,194,304
    // total ws use: 23,592,960 bytes

    k_convert_x<<<2048, 256, 0, stream>>>(x, xb);
    k_transpose_w<<<dim3(3, 256), 256, 0, stream>>>(Wqkv, wqkvT, 768);
    k_transpose_w<<<dim3(1, 256), 256, 0, stream>>>(Wproj, wprojT, 256);
    k_init_vpad<<<1024, 256, 0, stream>>>(vT);
    k_qkv<<<dim3(128, 12), 256, 0, stream>>>(xb, wqkvT, bqkv, qkbuf, vT);
    k_attn<<<1024, 256, 0, stream>>>(qkbuf, vT, aoutb);
    k_proj<<<dim3(128, 4), 256, 0, stream>>>(aoutb, wprojT, bproj, out);
}

// Round 5
// 290.645 us; speedup vs baseline: 1.1830x; 1.1830x over previous
//
#include <hip/hip_runtime.h>

#define NSEQ 4096
#define BATCH 2
#define ROWS (BATCH * NSEQ)   // 8192
#define NH 8
#define DHD 32

typedef __attribute__((ext_vector_type(8))) short bf16x8;
typedef __attribute__((ext_vector_type(4))) float f32x4;

static __device__ __forceinline__ ushort f2bf(float f) {
    union { float f; uint u; } v; v.f = f;
    uint u = v.u;
    uint r = (u + 0x7fffu + ((u >> 16) & 1u)) >> 16;   // RTNE
    return (ushort)r;
}

// ---------------- prep: x fp32 -> bf16 ----------------
__global__ __launch_bounds__(256) void k_convert_x(const float* __restrict__ x,
                                                   ushort* __restrict__ xb) {
    int i = (blockIdx.x * 256 + threadIdx.x) * 4;   // total 2097152 elems
    float4 v = *(const float4*)(x + i);
    ushort4 o;
    o.x = f2bf(v.x); o.y = f2bf(v.y); o.z = f2bf(v.z); o.w = f2bf(v.w);
    *(ushort4*)(xb + i) = o;
}

// ---------------- prep: W [K=256][ncols] fp32 -> Wt [ncols][256] bf16 ----------------
__global__ __launch_bounds__(256) void k_transpose_w(const float* __restrict__ w,
                                                     ushort* __restrict__ wt, int ncols) {
    int n = blockIdx.x * 256 + threadIdx.x;
    int k = blockIdx.y;   // 0..255
    wt[n * 256 + k] = f2bf(w[k * ncols + n]);
}

// ---------------- QKV GEMM: [8192x256]bf16 @ Wt[768][256] + bias ----------------
// writes: qk [8192][512] (cols 0..255 = Q*(1/16), 256..511 = K),
//         vT [16][32][4096] with columns PERMUTED within each 64-block by
//         sigma^-1(s) = bits {s5,s3,s2,s4,s1,s0} so PV A-fragments come
//         directly from the S^T register layout (no LDS P round-trip).
__global__ __launch_bounds__(256) void k_qkv(const ushort* __restrict__ xb,
                                             const ushort* __restrict__ wt,
                                             const float* __restrict__ bias,
                                             ushort* __restrict__ qk,
                                             ushort* __restrict__ vT) {
    int w = threadIdx.x >> 6, lane = threadIdx.x & 63;
    int lhi = lane >> 4, llo = lane & 15;
    int row0 = blockIdx.x * 64 + w * 16;
    int n0 = blockIdx.y * 64;

    f32x4 acc[4] = {};
#pragma unroll
    for (int ks = 0; ks < 8; ++ks) {
        int k0 = ks * 32 + lhi * 8;
        bf16x8 a = *(const bf16x8*)(xb + (row0 + llo) * 256 + k0);
#pragma unroll
        for (int fn = 0; fn < 4; ++fn) {
            bf16x8 b = *(const bf16x8*)(wt + (n0 + fn * 16 + llo) * 256 + k0);
            acc[fn] = __builtin_amdgcn_mfma_f32_16x16x32_bf16(a, b, acc[fn], 0, 0, 0);
        }
    }
#pragma unroll
    for (int fn = 0; fn < 4; ++fn) {
        int cg = n0 + fn * 16 + llo;
        int three = cg >> 8, rem = cg & 255;
        float bv = bias[cg];
#pragma unroll
        for (int r = 0; r < 4; ++r) {
            int row = row0 + lhi * 4 + r;
            float v = acc[fn][r] + bv;
            if (three == 0) {
                qk[row * 512 + rem] = f2bf(v * 0.0625f);   // pre-scale Q by C^-0.5 = 1/16
            } else if (three == 1) {
                qk[row * 512 + 256 + rem] = f2bf(v);
            } else {
                int bb = row >> 12, n = row & 4095;
                int hh = rem >> 5, dh = rem & 31;
                int s = n & 63;
                int np = (n & ~63) | ((s >> 5) << 5) | (((s & 15) >> 2) << 3)
                       | (((s >> 4) & 1) << 2) | (s & 3);
                vT[((size_t)(bb * NH + hh) * DHD + dh) * NSEQ + np] = f2bf(v);
            }
        }
    }
}

// ---------------- flash attention: 1 wave = 16 q-rows x 4096 keys ----------------
// Round-2 proven structure, minus the LDS P tile: PV A-fragments built in-register
// from S^T via cvt_pk (V columns pre-permuted in k_qkv). K double-buffered in regs.
// deferred-max (THR=8), l via ones-col MFMA (constant B frag).
__global__ __launch_bounds__(256, 4) void k_attn(const ushort* __restrict__ qk,
                                                 const ushort* __restrict__ vT,
                                                 ushort* __restrict__ attn_out) {
    int w = threadIdx.x >> 6, lane = threadIdx.x & 63;
    int lhi = lane >> 4, llo = lane & 15;
    int wid = blockIdx.x * 4 + w;          // 0..4095
    int bh = wid >> 8;                     // 0..15 (b*8+h)
    int qt = wid & 255;
    int b = bh >> 3, h = bh & 7;
    int q0 = qt * 16;

    const ushort* qbase = qk + (size_t)(b * NSEQ) * 512 + h * DHD;
    const ushort* kbase = qbase + 256;
    const ushort* vbase = vT + (size_t)bh * DHD * NSEQ;
    const ushort* pv0 = vbase + llo * NSEQ + lhi * 8;
    const ushort* pv1 = vbase + (llo + 16) * NSEQ + lhi * 8;
    const ushort* pk0 = kbase + llo * 512 + lhi * 8;

    bf16x8 qf = *(const bf16x8*)(qbase + (q0 + llo) * 512 + lhi * 8);
    // constant ones-column B fragment: col llo==0 gets 1.0 for all k
    short onebits = (llo == 0) ? (short)0x3F80 : (short)0;
    bf16x8 va2 = {onebits, onebits, onebits, onebits, onebits, onebits, onebits, onebits};

    f32x4 acc0 = {}, acc1 = {}, acc2 = {};
    const float L2E = 1.4426950408889634f;
    float mrun = 0.f;      // deferred running max for q-row llo
    float nmL2E = 0.f;     // -mrun * L2E
    float mthr = 8.f;      // mrun + THR
    const f32x4 zf = {0.f, 0.f, 0.f, 0.f};

    // one 64-key tile: S^T mfma -> deferred-max -> exp+cvt_pk -> PV mfma (no LDS)
    auto TILE = [&](const bf16x8& k0, const bf16x8& k1, const bf16x8& k2,
                    const bf16x8& k3, int KV) {
        // V loads issued first (latency overlap with S+softmax)
        bf16x8 v00 = *(const bf16x8*)(pv0 + KV);
        bf16x8 v01 = *(const bf16x8*)(pv1 + KV);
        bf16x8 v10 = *(const bf16x8*)(pv0 + KV + 32);
        bf16x8 v11 = *(const bf16x8*)(pv1 + KV + 32);
        // S^T: lane holds S[q=llo][key = KV + st*16 + lhi*4 + r]
        f32x4 sf0 = __builtin_amdgcn_mfma_f32_16x16x32_bf16(k0, qf, zf, 0, 0, 0);
        f32x4 sf1 = __builtin_amdgcn_mfma_f32_16x16x32_bf16(k1, qf, zf, 0, 0, 0);
        f32x4 sf2 = __builtin_amdgcn_mfma_f32_16x16x32_bf16(k2, qf, zf, 0, 0, 0);
        f32x4 sf3 = __builtin_amdgcn_mfma_f32_16x16x32_bf16(k3, qf, zf, 0, 0, 0);
        // per-lane partial max; deferred-max check (no shuffles in fast path)
        float t0 = fmaxf(fmaxf(sf0[0], sf0[1]), fmaxf(sf0[2], sf0[3]));
        float t1 = fmaxf(fmaxf(sf1[0], sf1[1]), fmaxf(sf1[2], sf1[3]));
        float t2 = fmaxf(fmaxf(sf2[0], sf2[1]), fmaxf(sf2[2], sf2[3]));
        float t3 = fmaxf(fmaxf(sf3[0], sf3[1]), fmaxf(sf3[2], sf3[3]));
        float tm = fmaxf(fmaxf(t0, t1), fmaxf(t2, t3));
        if (!__all(tm <= mthr)) {
            float rmax = fmaxf(tm, __shfl_xor(tm, 16));
            rmax = fmaxf(rmax, __shfl_xor(rmax, 32));
            float mnew = fmaxf(mrun, rmax);
            float corr = __builtin_amdgcn_exp2f((mrun - mnew) * L2E);
            mrun = mnew; nmL2E = -mrun * L2E; mthr = mrun + 8.f;
#pragma unroll
            for (int r = 0; r < 4; ++r) {
                float fc = __shfl(corr, lhi * 4 + r);
                acc0[r] *= fc; acc1[r] *= fc; acc2[r] *= fc;
            }
        }
        // exp2 then pack: pa0 = [sf0, sf1] pairs, pa1 = [sf2, sf3] pairs.
        float e00 = __builtin_amdgcn_exp2f(__builtin_fmaf(sf0[0], L2E, nmL2E));
        float e01 = __builtin_amdgcn_exp2f(__builtin_fmaf(sf0[1], L2E, nmL2E));
        float e02 = __builtin_amdgcn_exp2f(__builtin_fmaf(sf0[2], L2E, nmL2E));
        float e03 = __builtin_amdgcn_exp2f(__builtin_fmaf(sf0[3], L2E, nmL2E));
        float e10 = __builtin_amdgcn_exp2f(__builtin_fmaf(sf1[0], L2E, nmL2E));
        float e11 = __builtin_amdgcn_exp2f(__builtin_fmaf(sf1[1], L2E, nmL2E));
        float e12 = __builtin_amdgcn_exp2f(__builtin_fmaf(sf1[2], L2E, nmL2E));
        float e13 = __builtin_amdgcn_exp2f(__builtin_fmaf(sf1[3], L2E, nmL2E));
        float e20 = __builtin_amdgcn_exp2f(__builtin_fmaf(sf2[0], L2E, nmL2E));
        float e21 = __builtin_amdgcn_exp2f(__builtin_fmaf(sf2[1], L2E, nmL2E));
        float e22 = __builtin_amdgcn_exp2f(__builtin_fmaf(sf2[2], L2E, nmL2E));
        float e23 = __builtin_amdgcn_exp2f(__builtin_fmaf(sf2[3], L2E, nmL2E));
        float e30 = __builtin_amdgcn_exp2f(__builtin_fmaf(sf3[0], L2E, nmL2E));
        float e31 = __builtin_amdgcn_exp2f(__builtin_fmaf(sf3[1], L2E, nmL2E));
        float e32 = __builtin_amdgcn_exp2f(__builtin_fmaf(sf3[2], L2E, nmL2E));
        float e33 = __builtin_amdgcn_exp2f(__builtin_fmaf(sf3[3], L2E, nmL2E));
        union PU { uint u[4]; bf16x8 v; };
        PU pa0, pa1;
        asm("v_cvt_pk_bf16_f32 %0, %1, %2" : "=v"(pa0.u[0]) : "v"(e00), "v"(e01));
        asm("v_cvt_pk_bf16_f32 %0, %1, %2" : "=v"(pa0.u[1]) : "v"(e02), "v"(e03));
        asm("v_cvt_pk_bf16_f32 %0, %1, %2" : "=v"(pa0.u[2]) : "v"(e10), "v"(e11));
        asm("v_cvt_pk_bf16_f32 %0, %1, %2" : "=v"(pa0.u[3]) : "v"(e12), "v"(e13));
        asm("v_cvt_pk_bf16_f32 %0, %1, %2" : "=v"(pa1.u[0]) : "v"(e20), "v"(e21));
        asm("v_cvt_pk_bf16_f32 %0, %1, %2" : "=v"(pa1.u[1]) : "v"(e22), "v"(e23));
        asm("v_cvt_pk_bf16_f32 %0, %1, %2" : "=v"(pa1.u[2]) : "v"(e30), "v"(e31));
        asm("v_cvt_pk_bf16_f32 %0, %1, %2" : "=v"(pa1.u[3]) : "v"(e32), "v"(e33));
        // PV: V columns pre-permuted so pa maps positions correctly
        acc0 = __builtin_amdgcn_mfma_f32_16x16x32_bf16(pa0.v, v00, acc0, 0, 0, 0);
        acc1 = __builtin_amdgcn_mfma_f32_16x16x32_bf16(pa0.v, v01, acc1, 0, 0, 0);
        acc2 = __builtin_amdgcn_mfma_f32_16x16x32_bf16(pa0.v, va2, acc2, 0, 0, 0);
        acc0 = __builtin_amdgcn_mfma_f32_16x16x32_bf16(pa1.v, v10, acc0, 0, 0, 0);
        acc1 = __builtin_amdgcn_mfma_f32_16x16x32_bf16(pa1.v, v11, acc1, 0, 0, 0);
        acc2 = __builtin_amdgcn_mfma_f32_16x16x32_bf16(pa1.v, va2, acc2, 0, 0, 0);
    };

    // K double-buffer: prefetch next 64-key tile while computing current
    bf16x8 kA0, kA1, kA2, kA3, kB0, kB1, kB2, kB3;
    kA0 = *(const bf16x8*)(pk0);
    kA1 = *(const bf16x8*)(pk0 + 16 * 512);
    kA2 = *(const bf16x8*)(pk0 + 32 * 512);
    kA3 = *(const bf16x8*)(pk0 + 48 * 512);
    for (int kv = 0; kv < NSEQ; kv += 128) {
        kB0 = *(const bf16x8*)(pk0 + (kv + 64) * 512);
        kB1 = *(const bf16x8*)(pk0 + (kv + 80) * 512);
        kB2 = *(const bf16x8*)(pk0 + (kv + 96) * 512);
        kB3 = *(const bf16x8*)(pk0 + (kv + 112) * 512);
        TILE(kA0, kA1, kA2, kA3, kv);
        if (kv + 128 < NSEQ) {
            kA0 = *(const bf16x8*)(pk0 + (kv + 128) * 512);
            kA1 = *(const bf16x8*)(pk0 + (kv + 144) * 512);
            kA2 = *(const bf16x8*)(pk0 + (kv + 160) * 512);
            kA3 = *(const bf16x8*)(pk0 + (kv + 176) * 512);
        }
        TILE(kB0, kB1, kB2, kB3, kv + 64);
    }

    // epilogue: l[q-row lhi*4+r] lives in acc2[r] of lane lhi*16 (col 0)
#pragma unroll
    for (int r = 0; r < 4; ++r) {
        float ls = __shfl(acc2[r], lhi * 16);
        float li = 1.f / ls;
        int row = q0 + lhi * 4 + r;
        size_t orow = ((size_t)(b * NSEQ) + row) * 256 + h * DHD;
        attn_out[orow + llo] = f2bf(acc0[r] * li);
        attn_out[orow + 16 + llo] = f2bf(acc1[r] * li);
    }
}

// ---------------- proj GEMM: [8192x256]bf16 @ Wt[256][256] + bias -> fp32 ----------------
__global__ __launch_bounds__(256) void k_proj(const ushort* __restrict__ aout,
                                              const ushort* __restrict__ wt,
                                              const float* __restrict__ bias,
                                              float* __restrict__ out) {
    int w = threadIdx.x >> 6, lane = threadIdx.x & 63;
    int lhi = lane >> 4, llo = lane & 15;
    int row0 = blockIdx.x * 64 + w * 16;
    int n0 = blockIdx.y * 64;

    f32x4 acc[4] = {};
#pragma unroll
    for (int ks = 0; ks < 8; ++ks) {
        int k0 = ks * 32 + lhi * 8;
        bf16x8 a = *(const bf16x8*)(aout + (row0 + llo) * 256 + k0);
#pragma unroll
        for (int fn = 0; fn < 4; ++fn) {
            bf16x8 b = *(const bf16x8*)(wt + (n0 + fn * 16 + llo) * 256 + k0);
            acc[fn] = __builtin_amdgcn_mfma_f32_16x16x32_bf16(a, b, acc[fn], 0, 0, 0);
        }
    }
#pragma unroll
    for (int fn = 0; fn < 4; ++fn) {
        int cg = n0 + fn * 16 + llo;
        float bv = bias[cg];
#pragma unroll
        for (int r = 0; r < 4; ++r) {
            int row = row0 + lhi * 4 + r;
            out[(size_t)row * 256 + cg] = acc[fn][r] + bv;
        }
    }
}

extern "C" void kernel_launch(void* const* d_in, const int* in_sizes, int n_in,
                              void* d_out, int out_size, void* d_ws, size_t ws_size,
                              hipStream_t stream) {
    const float* x     = (const float*)d_in[0];
    const float* Wqkv  = (const float*)d_in[1];
    const float* bqkv  = (const float*)d_in[2];
    const float* Wproj = (const float*)d_in[3];
    const float* bproj = (const float*)d_in[4];
    float* out = (float*)d_out;

    char* ws = (char*)d_ws;
    ushort* xb     = (ushort*)(ws);                 // 8192*256*2   = 4,194,304
    ushort* wqkvT  = (ushort*)(ws + 4194304);       // 768*256*2    =   393,216
    ushort* wprojT = (ushort*)(ws + 4587520);       // 256*256*2    =   131,072
    ushort* qkbuf  = (ushort*)(ws + 4718592);       // 8192*512*2   = 8,388,608
    ushort* vT     = (ushort*)(ws + 13107200);      // 16*32*4096*2 = 4,194,304
    ushort* aoutb  = (ushort*)(ws + 17301504);      // 8192*256*2   = 4,194,304
    // total ws use: 21,495,808 bytes (round-1/2 proven-safe layout)

    k_convert_x<<<2048, 256, 0, stream>>>(x, xb);
    k_transpose_w<<<dim3(3, 256), 256, 0, stream>>>(Wqkv, wqkvT, 768);
    k_transpose_w<<<dim3(1, 256), 256, 0, stream>>>(Wproj, wprojT, 256);
    k_qkv<<<dim3(128, 12), 256, 0, stream>>>(xb, wqkvT, bqkv, qkbuf, vT);
    k_attn<<<1024, 256, 0, stream>>>(qkbuf, vT, aoutb);
    k_proj<<<dim3(128, 4), 256, 0, stream>>>(aoutb, wprojT, bproj, out);
}